// Round 2
// baseline (15547.554 us; speedup 1.0000x reference)
//
#include <hip/hip_runtime.h>
#include <hip/hip_bf16.h>

#define TDIM 1024
#define HDIM 1024
#define IDIM 1024
#define BSZ  64

typedef __attribute__((ext_vector_type(4))) float  floatx4;
typedef __attribute__((ext_vector_type(8))) short  shortx8;

static __device__ __forceinline__ short f2bf(float x) {
    unsigned u = __builtin_bit_cast(unsigned, x);
    u += 0x7fffu + ((u >> 16) & 1u);           // round-to-nearest-even
    return (short)(u >> 16);
}

static __device__ __forceinline__ shortx8 pack8(floatx4 a, floatx4 b) {
    shortx8 r;
    r[0] = f2bf(a[0]); r[1] = f2bf(a[1]); r[2] = f2bf(a[2]); r[3] = f2bf(a[3]);
    r[4] = f2bf(b[0]); r[5] = f2bf(b[1]); r[6] = f2bf(b[2]); r[7] = f2bf(b[3]);
    return r;
}

// ---------------------------------------------------------------------------
// Phase A: out[m][n] = sum_k input[m][k] * W_ih[n][k] + b_ih[n] + b_hh[n]
// M = B*T = 65536, N = H = 1024, K = I = 1024.  bf16 MFMA, fp32 accum,
// fp32 result written straight into d_out (Phase B consumes it in place).
// 128x128 tile / WG (256 thr, 4 waves in 2x2, each wave 4x4 tiles of 16x16).
// ---------------------------------------------------------------------------
__global__ __launch_bounds__(256, 2)
void xp_gemm(const float* __restrict__ A, const float* __restrict__ W,
             const float* __restrict__ bih, const float* __restrict__ bhh,
             float* __restrict__ out)
{
    __shared__ short As[128 * 72];   // pitch 72 shorts -> 2-way (free) bank aliasing
    __shared__ short Bs[128 * 72];

    const int tid  = threadIdx.x;
    const int bx   = blockIdx.x;
    const int m0   = (bx >> 3) * 128;
    const int n0   = (bx & 7) * 128;
    const int lane = tid & 63;
    const int w    = tid >> 6;
    const int wm   = w & 1, wn = w >> 1;
    const int col  = lane & 15, quad = lane >> 4;

    const int srow = tid >> 1;          // 0..127
    const int scol = (tid & 1) * 32;    // 0 or 32
    const float* ap = A + (size_t)(m0 + srow) * IDIM + scol;
    const float* wp = W + (size_t)(n0 + srow) * IDIM + scol;
    short* asw = As + srow * 72 + scol;
    short* bsw = Bs + srow * 72 + scol;

    floatx4 acc[4][4];
#pragma unroll
    for (int i = 0; i < 4; i++)
#pragma unroll
        for (int j = 0; j < 4; j++) acc[i][j] = (floatx4){0.f, 0.f, 0.f, 0.f};

    for (int kt = 0; kt < IDIM; kt += 64) {
        floatx4 av[8], bv[8];
        const floatx4* pa = (const floatx4*)(ap + kt);
        const floatx4* pb = (const floatx4*)(wp + kt);
#pragma unroll
        for (int q = 0; q < 8; q++) { av[q] = pa[q]; bv[q] = pb[q]; }
        __syncthreads();                       // previous tile's reads done
#pragma unroll
        for (int q = 0; q < 4; q++) {
            *(shortx8*)(asw + q * 8) = pack8(av[2 * q], av[2 * q + 1]);
            *(shortx8*)(bsw + q * 8) = pack8(bv[2 * q], bv[2 * q + 1]);
        }
        __syncthreads();
#pragma unroll
        for (int kb = 0; kb < 64; kb += 32) {
            shortx8 af[4], bf[4];
#pragma unroll
            for (int i = 0; i < 4; i++)
                af[i] = *(const shortx8*)(As + (wm * 64 + i * 16 + col) * 72 + kb + quad * 8);
#pragma unroll
            for (int j = 0; j < 4; j++)
                bf[j] = *(const shortx8*)(Bs + (wn * 64 + j * 16 + col) * 72 + kb + quad * 8);
#pragma unroll
            for (int i = 0; i < 4; i++)
#pragma unroll
                for (int j = 0; j < 4; j++)
                    acc[i][j] = __builtin_amdgcn_mfma_f32_16x16x32_bf16(af[i], bf[j], acc[i][j], 0, 0, 0);
        }
    }

#pragma unroll
    for (int j = 0; j < 4; j++) {
        const int n = n0 + wn * 64 + j * 16 + col;
        const float bias = bih[n] + bhh[n];
#pragma unroll
        for (int i = 0; i < 4; i++) {
            const int mb = m0 + wm * 64 + i * 16 + quad * 4;
#pragma unroll
            for (int r = 0; r < 4; r++)
                out[(size_t)(mb + r) * HDIM + n] = acc[i][j][r] + bias;
        }
    }
}

// ---------------------------------------------------------------------------
// Phase B: recurrence. 64 WGs = 4 batch-groups (gm, 16 batches) x 16 n-WGs
// (gn, 64 neurons).  W_hh held in registers as B-fragments (128 VGPR/thread).
// Per-group counter barrier per step; h ping-pong fp32 in workspace.
// Regular launch: 64 blocks @ __launch_bounds__(256,1) on 256 CUs are
// trivially co-resident (capacity), no cooperative API needed.
// ---------------------------------------------------------------------------
__global__ __launch_bounds__(256, 1)
void rnn_rec(float* __restrict__ out,          // in: x_proj (fp32); overwritten with h
             const float* __restrict__ Whh, const float* __restrict__ h0,
             float* __restrict__ hbuf, unsigned* __restrict__ cnt)
{
    __shared__ short hlds[16 * 1032];   // 16 batches x 1024 k, pitch 1032 (2-way free)

    const int tid  = threadIdx.x;
    const int gm   = blockIdx.x >> 4;   // 0..3
    const int gn   = blockIdx.x & 15;   // 0..15
    const int lane = tid & 63;
    const int w    = tid >> 6;
    const int col  = lane & 15, quad = lane >> 4;
    const int nglob = gn * 64 + w * 16 + col;
    unsigned* mycnt = cnt + gm * 32;    // 128 B apart

    // B-fragments: W_hh[n][k], k = kb*32 + quad*8 + j  (j = 0..7)
    shortx8 bfrag[32];
    {
        const float* wrow = Whh + (size_t)nglob * HDIM + quad * 8;
#pragma unroll
        for (int kb = 0; kb < 32; kb++) {
            const floatx4* p = (const floatx4*)(wrow + kb * 32);
            bfrag[kb] = pack8(p[0], p[1]);
        }
    }

    const size_t slice = (size_t)gm * 16 * HDIM;

    for (int t = 0; t < TDIM; ++t) {
        // ---- stage h (fp32 global, agent-coherent) -> LDS bf16 ----
        const float* src = (t == 0) ? (h0 + slice)
                                    : (hbuf + (size_t)(t & 1) * (BSZ * HDIM) + slice);
        const unsigned long long* s8 = (const unsigned long long*)src;
        unsigned long long hv[32];
#pragma unroll
        for (int j = 0; j < 32; j++)
            hv[j] = __hip_atomic_load(s8 + j * 256 + tid, __ATOMIC_RELAXED, __HIP_MEMORY_SCOPE_AGENT);
        __syncthreads();                 // prior step's LDS reads done
#pragma unroll
        for (int j = 0; j < 32; j++) {
            const int e = (j * 256 + tid) * 2;
            const int m = e >> 10, k = e & 1023;
            float2 f = __builtin_bit_cast(float2, hv[j]);
            const int packed = ((int)(unsigned short)f2bf(f.x)) |
                               (((int)(unsigned short)f2bf(f.y)) << 16);
            *(int*)(hlds + m * 1032 + k) = packed;
        }
        __syncthreads();

        // ---- K loop: 32 MFMAs, B from registers ----
        floatx4 acc = (floatx4){0.f, 0.f, 0.f, 0.f};
#pragma unroll
        for (int kb = 0; kb < 32; kb++) {
            shortx8 af = *(const shortx8*)(hlds + col * 1032 + kb * 32 + quad * 8);
            acc = __builtin_amdgcn_mfma_f32_16x16x32_bf16(af, bfrag[kb], acc, 0, 0, 0);
        }

        // ---- epilogue: tanh, write out (fp32) + next-h (fp32, coherent) ----
        float* hout = hbuf + (size_t)((t + 1) & 1) * (BSZ * HDIM);
#pragma unroll
        for (int r = 0; r < 4; r++) {
            const int b = gm * 16 + quad * 4 + r;
            const size_t oidx = (size_t)b * (TDIM * HDIM) + (size_t)t * HDIM + nglob;
            const float h = tanhf(out[oidx] + acc[r]);
            out[oidx] = h;
            __hip_atomic_store(hout + (size_t)b * HDIM + nglob, h,
                               __ATOMIC_RELAXED, __HIP_MEMORY_SCOPE_AGENT);
            if (t == TDIM - 1)
                out[(size_t)BSZ * TDIM * HDIM + (size_t)b * HDIM + nglob] = h;
        }

        // ---- group barrier (16 WGs sharing gm) ----
        __threadfence();                 // release: h stores visible device-wide
        __syncthreads();
        if (tid == 0) {
            __hip_atomic_fetch_add(mycnt, 1u, __ATOMIC_RELAXED, __HIP_MEMORY_SCOPE_AGENT);
            const unsigned target = 16u * (unsigned)(t + 1);
            int guard = 0;
            while (__hip_atomic_load(mycnt, __ATOMIC_RELAXED, __HIP_MEMORY_SCOPE_AGENT) < target) {
                if (++guard > (1 << 20)) break;   // hang fuse
            }
        }
        __syncthreads();
        __threadfence();                 // acquire
    }
}

// ---------------------------------------------------------------------------
extern "C" void kernel_launch(void* const* d_in, const int* in_sizes, int n_in,
                              void* d_out, int out_size, void* d_ws, size_t ws_size,
                              hipStream_t stream)
{
    const float* input = (const float*)d_in[0];
    const float* h0    = (const float*)d_in[1];
    const float* W_ih  = (const float*)d_in[2];
    const float* b_ih  = (const float*)d_in[3];
    const float* W_hh  = (const float*)d_in[4];
    const float* b_hh  = (const float*)d_in[5];
    float* out = (float*)d_out;

    char* ws = (char*)d_ws;
    float*    hbuf = (float*)ws;                                   // 512 KiB ping-pong
    unsigned* cnt  = (unsigned*)(ws + (size_t)2 * BSZ * HDIM * 4); // 512 B counters

    hipMemsetAsync(cnt, 0, 512, stream);

    dim3 blk(256);
    xp_gemm<<<dim3(4096), blk, 0, stream>>>(input, W_ih, b_ih, b_hh, out);
    rnn_rec<<<dim3(64),   blk, 0, stream>>>(out, W_hh, h0, hbuf, cnt);
}